// Round 1
// baseline (273.089 us; speedup 1.0000x reference)
//
#include <hip/hip_runtime.h>
#include <hip/hip_bf16.h>

#define DD   4096   // hidden dim
#define NE   8      // experts
#define NR   16     // lora rank
#define NTOK 8192   // B*S
#define NDO  4096   // output dim
// SCALING = 16/16 = 1.0

typedef __attribute__((ext_vector_type(8))) __bf16 bf16x8;
typedef __attribute__((ext_vector_type(4))) float  f32x4;

__device__ __forceinline__ bf16x8 to_bf16x8(float4 a, float4 b) {
    bf16x8 r;
    r[0] = (__bf16)a.x; r[1] = (__bf16)a.y; r[2] = (__bf16)a.z; r[3] = (__bf16)a.w;
    r[4] = (__bf16)b.x; r[5] = (__bf16)b.y; r[6] = (__bf16)b.z; r[7] = (__bf16)b.w;
    return r;
}

// ---------------- k0: zero the per-expert counters ----------------
__global__ __launch_bounds__(64) void k_zero(int* __restrict__ count) {
    if (threadIdx.x < NE) count[threadIdx.x] = 0;
}

// ---------------- k1: routing (f64 logits) + expert binning ----------------
// grid 512 x 256 threads; each wave handles 4 consecutive tokens.
__global__ __launch_bounds__(256) void k_route(const float* __restrict__ x,
                                               const float* __restrict__ rw,
                                               float* __restrict__ w_arr,
                                               int*   __restrict__ token_list,
                                               int*   __restrict__ count) {
    const int wave = threadIdx.x >> 6;
    const int lane = threadIdx.x & 63;
    const int t0   = blockIdx.x * 16 + wave * 4;
    const float* xp = x + (size_t)t0 * DD;

    double acc[4][NE];
    #pragma unroll
    for (int t = 0; t < 4; t++)
        #pragma unroll
        for (int e = 0; e < NE; e++) acc[t][e] = 0.0;

    // lane covers d = (i*64 + lane)*4 .. +3  -> coalesced float4, full D
    for (int i = 0; i < 16; i++) {
        const int d4 = (i * 64 + lane) * 4;
        double xd[4][4];
        #pragma unroll
        for (int t = 0; t < 4; t++) {
            const float4 xv = *(const float4*)(xp + (size_t)t * DD + d4);
            xd[t][0] = xv.x; xd[t][1] = xv.y; xd[t][2] = xv.z; xd[t][3] = xv.w;
        }
        #pragma unroll
        for (int e = 0; e < NE; e++) {
            const float4 wv = *(const float4*)(rw + (size_t)e * DD + d4);
            const double w0 = wv.x, w1 = wv.y, w2 = wv.z, w3 = wv.w;
            #pragma unroll
            for (int t = 0; t < 4; t++) {
                acc[t][e] = fma(xd[t][0], w0, acc[t][e]);
                acc[t][e] = fma(xd[t][1], w1, acc[t][e]);
                acc[t][e] = fma(xd[t][2], w2, acc[t][e]);
                acc[t][e] = fma(xd[t][3], w3, acc[t][e]);
            }
        }
    }

    // full 64-lane butterfly (f64): every lane ends with complete sums
    #pragma unroll
    for (int off = 32; off > 0; off >>= 1) {
        #pragma unroll
        for (int t = 0; t < 4; t++)
            #pragma unroll
            for (int e = 0; e < NE; e++)
                acc[t][e] += __shfl_xor(acc[t][e], off, 64);
    }

    // lanes 0..3: argmax (first max, matches top_k tie-break) + scatter
    #pragma unroll
    for (int tt = 0; tt < 4; tt++) {
        if (lane == tt) {
            double best = acc[tt][0]; int be = 0;
            #pragma unroll
            for (int e = 1; e < NE; e++)
                if (acc[tt][e] > best) { best = acc[tt][e]; be = e; }
            const int tok = t0 + tt;
            w_arr[tok] = (float)best;          // SCALING == 1.0 folded here later
            const int pos = atomicAdd(&count[be], 1);
            token_list[be * NTOK + pos] = tok;
        }
    }
}

// ---------------- k2: fused h = x·A[e]^T  and  out = (w*h)·Bw[e]^T ----------------
// grid 8*512 WGs of 128 threads (2 waves). One WG = one 16-token tile of one expert.
// Wave wv does K-half of phase 1 and o-half of phase 2.
__global__ __launch_bounds__(128) void k_moe(const float* __restrict__ x,
                                             const float* __restrict__ Am,
                                             const float* __restrict__ Bw,
                                             const float* __restrict__ w_arr,
                                             const int*   __restrict__ token_list,
                                             const int*   __restrict__ count,
                                             float* __restrict__ out) {
    const int e    = blockIdx.x >> 9;
    const int g    = blockIdx.x & 511;
    const int cnt  = count[e];
    const int base = g * 16;
    if (base >= cnt) return;                  // uniform for the whole WG

    const int wv   = threadIdx.x >> 6;        // 0,1
    const int lane = threadIdx.x & 63;
    const int m    = lane & 15;               // A-row (token) for phase1 / a2-row for phase2
    const int half = lane >> 4;               // k-group 0..3

    const int  idx   = base + m;
    const bool valid = idx < cnt;
    const int  tok   = valid ? token_list[e * NTOK + idx] : 0;
    const float* xrow = x  + (size_t)tok * DD;
    const float* arow = Am + ((size_t)e * NR + m) * DD;   // b-frag: n = r = lane&15

    // ---- phase 1: partial h over this wave's K-half (invalid rows -> garbage, masked later)
    f32x4 acc = {0.f, 0.f, 0.f, 0.f};
    const int kbase = wv * 2048;
    #pragma unroll 2
    for (int ks = 0; ks < 64; ks++) {
        const int k0 = kbase + ks * 32 + half * 8;
        const float4 xa = *(const float4*)(xrow + k0);
        const float4 xb = *(const float4*)(xrow + k0 + 4);
        const float4 aa = *(const float4*)(arow + k0);
        const float4 ab = *(const float4*)(arow + k0 + 4);
        const bf16x8 af = to_bf16x8(xa, xb);
        const bf16x8 bf = to_bf16x8(aa, ab);
        acc = __builtin_amdgcn_mfma_f32_16x16x32_bf16(af, bf, acc, 0, 0, 0);
    }

    // ---- exchange: C layout row=(lane>>4)*4+reg, col=lane&15  ->  lds[wv][token][r]
    __shared__ float lds[2][16][20];          // pad 20 to spread banks
    #pragma unroll
    for (int r = 0; r < 4; r++) lds[wv][half * 4 + r][m] = acc[r];
    __syncthreads();

    // ---- a2 frag: wh[m][k], k = half*8+j (real for k<16, zero-padded to 32)
    const float wtok = valid ? w_arr[tok] : 0.f;   // also zeroes invalid rows
    bf16x8 a2;
    if (half < 2) {
        #pragma unroll
        for (int j = 0; j < 8; j++) {
            const int kk = half * 8 + j;
            a2[j] = (__bf16)((lds[0][m][kk] + lds[1][m][kk]) * wtok);
        }
    } else {
        #pragma unroll
        for (int j = 0; j < 8; j++) a2[j] = (__bf16)0.0f;
    }

    // tokens/validity for C rows (row = half*4 + reg)
    int trow[4]; bool vrow[4];
    #pragma unroll
    for (int r = 0; r < 4; r++) {
        const int ir = base + half * 4 + r;
        vrow[r] = ir < cnt;
        trow[r] = vrow[r] ? token_list[e * NTOK + ir] : 0;
    }

    // ---- phase 2: out tile = wh(16x16, padded K=32) @ BwT(16x4096), wave covers 2048 o
    const float* bwe = Bw + (size_t)e * NDO * NR;
    const int h2 = (half < 2) ? half : 0;     // lanes 32..63 load dup, frag zeroed
    const f32x4 zero = {0.f, 0.f, 0.f, 0.f};
    #pragma unroll 2
    for (int ot = wv * 128; ot < wv * 128 + 128; ot++) {
        const int obase = ot * 16;
        const float* bp = bwe + (size_t)(obase + m) * NR + h2 * 8;
        const float4 p = *(const float4*)(bp);
        const float4 q = *(const float4*)(bp + 4);
        bf16x8 b2 = to_bf16x8(p, q);
        if (half >= 2) {
            #pragma unroll
            for (int j = 0; j < 8; j++) b2[j] = (__bf16)0.0f;
        }
        const f32x4 d = __builtin_amdgcn_mfma_f32_16x16x32_bf16(a2, b2, zero, 0, 0, 0);
        #pragma unroll
        for (int r = 0; r < 4; r++) {
            if (vrow[r]) out[(size_t)trow[r] * NDO + obase + m] = d[r];
        }
    }
}

// ---------------- launcher ----------------
extern "C" void kernel_launch(void* const* d_in, const int* in_sizes, int n_in,
                              void* d_out, int out_size, void* d_ws, size_t ws_size,
                              hipStream_t stream) {
    const float* x  = (const float*)d_in[0];
    const float* rw = (const float*)d_in[1];
    const float* Am = (const float*)d_in[2];
    const float* Bw = (const float*)d_in[3];
    float* out = (float*)d_out;

    char* ws = (char*)d_ws;
    int*   count      = (int*)ws;                 // 8 ints
    float* w_arr      = (float*)(ws + 512);       // 8192 f32
    int*   token_list = (int*)(ws + 65536);       // 8*8192 ints (fixed-stride bins)

    hipLaunchKernelGGL(k_zero,  dim3(1),    dim3(64),  0, stream, count);
    hipLaunchKernelGGL(k_route, dim3(512),  dim3(256), 0, stream, x, rw, w_arr, token_list, count);
    hipLaunchKernelGGL(k_moe,   dim3(4096), dim3(128), 0, stream, x, Am, Bw, w_arr, token_list, count, out);
}

// Round 2
// 180.633 us; speedup vs baseline: 1.5118x; 1.5118x over previous
//
#include <hip/hip_runtime.h>
#include <hip/hip_bf16.h>

#define DD   4096   // hidden dim
#define NE   8      // experts
#define NR   16     // lora rank
#define NTOK 8192   // B*S
#define NDO  4096   // output dim
// SCALING = 16/16 = 1.0

typedef __attribute__((ext_vector_type(8))) __bf16 bf16x8;
typedef __attribute__((ext_vector_type(4))) float  f32x4;

__device__ __forceinline__ bf16x8 to_bf16x8(float4 a, float4 b) {
    bf16x8 r;
    r[0] = (__bf16)a.x; r[1] = (__bf16)a.y; r[2] = (__bf16)a.z; r[3] = (__bf16)a.w;
    r[4] = (__bf16)b.x; r[5] = (__bf16)b.y; r[6] = (__bf16)b.z; r[7] = (__bf16)b.w;
    return r;
}

// ---------------- k0: zero the per-expert counters ----------------
__global__ __launch_bounds__(64) void k_zero(int* __restrict__ count) {
    if (threadIdx.x < NE) count[threadIdx.x] = 0;
}

// ---------------- k1: routing (f64 logits) + expert binning ----------------
// 512 blocks x 256 threads; block = 16 tokens (4 waves x 4 tokens).
// route_w staged through LDS in 32KB chunks: rw L2 traffic 256MB -> 64MB.
__global__ __launch_bounds__(256) void k_route(const float* __restrict__ x,
                                               const float* __restrict__ rw,
                                               float* __restrict__ w_arr,
                                               int*   __restrict__ token_list,
                                               int*   __restrict__ count) {
    const int wave = threadIdx.x >> 6;
    const int lane = threadIdx.x & 63;
    const int t0   = blockIdx.x * 16 + wave * 4;
    const float* xp = x + (size_t)t0 * DD;

    __shared__ float rws[NE][1024];   // 32 KB chunk of route_w

    double acc[4][NE];
    #pragma unroll
    for (int t = 0; t < 4; t++)
        #pragma unroll
        for (int e = 0; e < NE; e++) acc[t][e] = 0.0;

    for (int c = 0; c < 4; c++) {
        __syncthreads();              // protect previous chunk's readers
        #pragma unroll
        for (int i = 0; i < 8; i++) {
            const int j  = i * 256 + threadIdx.x;   // float4 slot 0..2047
            const int e  = j >> 8;
            const int d4 = (j & 255) * 4;
            *(float4*)&rws[e][d4] =
                *(const float4*)(rw + (size_t)e * DD + c * 1024 + d4);
        }
        __syncthreads();

        #pragma unroll
        for (int i = 0; i < 4; i++) {
            const int dc = (i * 64 + lane) * 4;     // 0..1023 within chunk
            double xd[4][4];
            #pragma unroll
            for (int t = 0; t < 4; t++) {
                const float4 xv = *(const float4*)(xp + (size_t)t * DD + c * 1024 + dc);
                xd[t][0] = xv.x; xd[t][1] = xv.y; xd[t][2] = xv.z; xd[t][3] = xv.w;
            }
            #pragma unroll
            for (int e = 0; e < NE; e++) {
                const float4 wv = *(const float4*)&rws[e][dc];
                const double w0 = wv.x, w1 = wv.y, w2 = wv.z, w3 = wv.w;
                #pragma unroll
                for (int t = 0; t < 4; t++) {
                    acc[t][e] = fma(xd[t][0], w0, acc[t][e]);
                    acc[t][e] = fma(xd[t][1], w1, acc[t][e]);
                    acc[t][e] = fma(xd[t][2], w2, acc[t][e]);
                    acc[t][e] = fma(xd[t][3], w3, acc[t][e]);
                }
            }
        }
    }

    // 64-lane butterfly (f64): every lane ends with complete sums
    #pragma unroll
    for (int off = 32; off > 0; off >>= 1) {
        #pragma unroll
        for (int t = 0; t < 4; t++)
            #pragma unroll
            for (int e = 0; e < NE; e++)
                acc[t][e] += __shfl_xor(acc[t][e], off, 64);
    }

    #pragma unroll
    for (int tt = 0; tt < 4; tt++) {
        if (lane == tt) {
            double best = acc[tt][0]; int be = 0;
            #pragma unroll
            for (int e = 1; e < NE; e++)
                if (acc[tt][e] > best) { best = acc[tt][e]; be = e; }
            const int tok = t0 + tt;
            w_arr[tok] = (float)best;
            const int pos = atomicAdd(&count[be], 1);
            token_list[be * NTOK + pos] = tok;
        }
    }
}

// ---------------- k2: wh[tok][r] = w * (x . A[e]^T)  (bf16 out) ----------------
// grid 8*512 WGs of 512 threads (8 waves, K=512 slice each). One WG = 16-token tile.
__global__ __launch_bounds__(512) void k_h(const float* __restrict__ x,
                                           const float* __restrict__ Am,
                                           const float* __restrict__ w_arr,
                                           const int*   __restrict__ token_list,
                                           const int*   __restrict__ count,
                                           __hip_bfloat16* __restrict__ wh) {
    const int e    = blockIdx.x >> 9;
    const int g    = blockIdx.x & 511;
    const int cnt  = count[e];
    const int base = g * 16;
    if (base >= cnt) return;

    const int wv   = threadIdx.x >> 6;        // 0..7
    const int lane = threadIdx.x & 63;
    const int m    = lane & 15;               // token row / A-row (r)
    const int half = lane >> 4;

    const int  idx   = base + m;
    const bool valid = idx < cnt;
    const int  tok   = valid ? token_list[e * NTOK + idx] : 0;
    const float* xrow = x  + (size_t)tok * DD;
    const float* arow = Am + ((size_t)e * NR + m) * DD;

    f32x4 acc = {0.f, 0.f, 0.f, 0.f};
    const int kbase = wv * 512;
    #pragma unroll 4
    for (int ks = 0; ks < 16; ks++) {
        const int k0 = kbase + ks * 32 + half * 8;
        const float4 xa = *(const float4*)(xrow + k0);
        const float4 xb = *(const float4*)(xrow + k0 + 4);
        const float4 aa = *(const float4*)(arow + k0);
        const float4 ab = *(const float4*)(arow + k0 + 4);
        const bf16x8 af = to_bf16x8(xa, xb);
        const bf16x8 bf = to_bf16x8(aa, ab);
        acc = __builtin_amdgcn_mfma_f32_16x16x32_bf16(af, bf, acc, 0, 0, 0);
    }

    // C layout: row = (lane>>4)*4 + reg (token), col = lane&15 (r)
    __shared__ float lds[8][16][20];
    #pragma unroll
    for (int r = 0; r < 4; r++) lds[wv][half * 4 + r][m] = acc[r];
    __syncthreads();

    if (threadIdx.x < 256) {
        const int t = threadIdx.x >> 4;
        const int r = threadIdx.x & 15;
        const int i2 = base + t;
        if (i2 < cnt) {
            float s = 0.f;
            #pragma unroll
            for (int w = 0; w < 8; w++) s += lds[w][t][r];
            const int tk = token_list[e * NTOK + i2];
            wh[(size_t)tk * NR + r] = (__hip_bfloat16)(s * w_arr[tk]);
        }
    }
}

// ---------------- k3: out = wh . Bw[e]^T ----------------
// grid 8*512*4 WGs of 256 threads. block = 16-token tile x 1024-output chunk;
// wave = 256 outputs (16 o-tiles).
__global__ __launch_bounds__(256) void k_out(const float* __restrict__ Bw,
                                             const __hip_bfloat16* __restrict__ wh,
                                             const int*   __restrict__ token_list,
                                             const int*   __restrict__ count,
                                             float* __restrict__ out) {
    const int bx    = blockIdx.x;
    const int chunk = bx & 3;
    const int slot  = (bx >> 2) & 511;
    const int e     = bx >> 11;
    const int cnt   = count[e];
    const int base  = slot * 16;
    if (base >= cnt) return;

    const int wv   = threadIdx.x >> 6;        // 0..3
    const int lane = threadIdx.x & 63;
    const int m    = lane & 15;
    const int half = lane >> 4;

    const int  idx   = base + m;
    const bool valid = idx < cnt;
    const int  tok   = valid ? token_list[e * NTOK + idx] : 0;

    // a2 frag: wh[m-token][k], k = half*8+j for half<2, zero-padded K=32
    bf16x8 a2;
    if (half < 2 && valid) {
        a2 = *(const bf16x8*)(wh + (size_t)tok * NR + half * 8);
    } else {
        #pragma unroll
        for (int j = 0; j < 8; j++) a2[j] = (__bf16)0.0f;
    }

    int trow[4]; bool vrow[4];
    #pragma unroll
    for (int r = 0; r < 4; r++) {
        const int ir = base + half * 4 + r;
        vrow[r] = ir < cnt;
        trow[r] = vrow[r] ? token_list[e * NTOK + ir] : 0;
    }

    const float* bwe = Bw + (size_t)e * NDO * NR;
    const int h2 = (half < 2) ? half : 0;
    const f32x4 zero4 = {0.f, 0.f, 0.f, 0.f};
    const int ob0 = chunk * 1024 + wv * 256;

    #pragma unroll 4
    for (int ot = 0; ot < 16; ot++) {
        const int obase = ob0 + ot * 16;
        const float* bp = bwe + (size_t)(obase + m) * NR + h2 * 8;
        const float4 p = *(const float4*)(bp);
        const float4 q = *(const float4*)(bp + 4);
        bf16x8 b2 = to_bf16x8(p, q);
        if (half >= 2) {
            #pragma unroll
            for (int j = 0; j < 8; j++) b2[j] = (__bf16)0.0f;
        }
        const f32x4 d = __builtin_amdgcn_mfma_f32_16x16x32_bf16(a2, b2, zero4, 0, 0, 0);
        #pragma unroll
        for (int r = 0; r < 4; r++) {
            if (vrow[r]) out[(size_t)trow[r] * NDO + obase + m] = d[r];
        }
    }
}

// ---------------- launcher ----------------
extern "C" void kernel_launch(void* const* d_in, const int* in_sizes, int n_in,
                              void* d_out, int out_size, void* d_ws, size_t ws_size,
                              hipStream_t stream) {
    const float* x  = (const float*)d_in[0];
    const float* rw = (const float*)d_in[1];
    const float* Am = (const float*)d_in[2];
    const float* Bw = (const float*)d_in[3];
    float* out = (float*)d_out;

    char* ws = (char*)d_ws;
    int*   count      = (int*)ws;                           // 8 ints
    float* w_arr      = (float*)(ws + 512);                 // 8192 f32
    int*   token_list = (int*)(ws + 65536);                 // 8*8192 ints
    __hip_bfloat16* wh = (__hip_bfloat16*)(ws + 65536 + NE * NTOK * 4); // 8192*16 bf16

    hipLaunchKernelGGL(k_zero,  dim3(1),     dim3(64),  0, stream, count);
    hipLaunchKernelGGL(k_route, dim3(512),   dim3(256), 0, stream, x, rw, w_arr, token_list, count);
    hipLaunchKernelGGL(k_h,     dim3(4096),  dim3(512), 0, stream, x, Am, w_arr, token_list, count, wh);
    hipLaunchKernelGGL(k_out,   dim3(16384), dim3(256), 0, stream, Bw, wh, token_list, count, out);
}